// Round 7
// baseline (215.856 us; speedup 1.0000x reference)
//
#include <hip/hip_runtime.h>

#define EMBED 1024
#define C3    3072
#define NHEAD 16
#define HDIM  64
#define BB    4
#define TT    2048
#define MTOK  8192   // BB*TT

typedef __bf16 bf16;
typedef __bf16 bf16x4 __attribute__((ext_vector_type(4)));
typedef __bf16 bf16x8 __attribute__((ext_vector_type(8)));
typedef float  f32x4  __attribute__((ext_vector_type(4)));
typedef float  f32x16 __attribute__((ext_vector_type(16)));
typedef unsigned int u32;

__device__ __forceinline__ void gload_lds16(const bf16* g, bf16* l) {
  __builtin_amdgcn_global_load_lds((__attribute__((address_space(1))) void*)g,
                                   (__attribute__((address_space(3))) void*)l,
                                   16, 0, 0);
}

__device__ __forceinline__ u32 pkbf(float lo, float hi_) {
  union { bf16 h[2]; u32 w; } u;
  u.h[0] = (bf16)lo; u.h[1] = (bf16)hi_;
  return u.w;
}

union upw { u32 w[4]; bf16x8 v; };

// ---------------- fp32 -> bf16 convert ----------------
__global__ __launch_bounds__(256) void cvt_kernel(const float* __restrict__ in,
                                                  bf16* __restrict__ out, int n) {
  int i = (blockIdx.x * blockDim.x + threadIdx.x) * 4;
  if (i >= n) return;
  float4 v = *reinterpret_cast<const float4*>(in + i);
  bf16x4 o;
  o[0] = (bf16)v.x; o[1] = (bf16)v.y; o[2] = (bf16)v.z; o[3] = (bf16)v.w;
  *reinterpret_cast<bf16x4*>(out + i) = o;
}

// ================= GEMM core (BK=64, swizzled LDS) =================
// lA/lB: [128 rows][64 k], 16B-chunk XOR swizzle: chunk c of row stored at c^(row&7).
// Computes acc[i][j] for the calling wave's 64x64 quadrant (wm, wn).
__device__ __forceinline__ void gemm_core(const bf16* __restrict__ A,
                                          const bf16* __restrict__ W,
                                          int K, int bm0, int bn0,
                                          int wm, int wn, int l15, int lg,
                                          f32x4 (&acc)[4][4]) {
  __shared__ __align__(16) bf16 lA[128 * 64];
  __shared__ __align__(16) bf16 lB[128 * 64];
  const int tid  = threadIdx.x;
  const int grow = tid >> 3;
  const int gseg = tid & 7;

  for (int kt = 0; kt < K; kt += 64) {
#pragma unroll
    for (int r = 0; r < 4; ++r) {
      const int row = r * 32 + grow;
      const int seg = gseg ^ (row & 7);
      gload_lds16(A + (size_t)(bm0 + row) * K + kt + seg * 8, &lA[(r * 256 + tid) * 8]);
      gload_lds16(W + (size_t)(bn0 + row) * K + kt + seg * 8, &lB[(r * 256 + tid) * 8]);
    }
    __syncthreads();
    const char* Ab = (const char*)lA;
    const char* Bb = (const char*)lB;
#pragma unroll
    for (int kk = 0; kk < 2; ++kk) {
      bf16x8 af[4], bf_[4];
#pragma unroll
      for (int i = 0; i < 4; ++i) {
        const int row = wm + i * 16 + l15;
        af[i] = *reinterpret_cast<const bf16x8*>(
            Ab + row * 128 + ((kk * 64 + lg * 16) ^ ((row & 7) << 4)));
      }
#pragma unroll
      for (int j = 0; j < 4; ++j) {
        const int row = wn + j * 16 + l15;
        bf_[j] = *reinterpret_cast<const bf16x8*>(
            Bb + row * 128 + ((kk * 64 + lg * 16) ^ ((row & 7) << 4)));
      }
#pragma unroll
      for (int i = 0; i < 4; ++i)
#pragma unroll
        for (int j = 0; j < 4; ++j)
          acc[i][j] = __builtin_amdgcn_mfma_f32_16x16x32_bf16(af[i], bf_[j],
                                                              acc[i][j], 0, 0, 0);
    }
    __syncthreads();
  }
}

// ---------------- GEMM1: qkv = x @ qkv_w^T + b, split into per-head layouts --------
__global__ __launch_bounds__(256) void gemm_qkv(const bf16* __restrict__ A,   // [8192][1024]
                                                const bf16* __restrict__ W,   // [3072][1024]
                                                const float* __restrict__ bias,
                                                bf16* __restrict__ Qh,
                                                bf16* __restrict__ Kh,
                                                bf16* __restrict__ VhT) {
  const int tid  = threadIdx.x;
  const int lane = tid & 63, wave = tid >> 6;
  const int wm   = (wave >> 1) * 64;
  const int wn   = (wave & 1) * 64;
  const int bn0  = blockIdx.x * 128;
  const int bm0  = blockIdx.y * 128;
  const int l15  = lane & 15, lg = lane >> 4;

  f32x4 acc[4][4] = {};
  gemm_core(A, W, EMBED, bm0, bn0, wm, wn, l15, lg, acc);

  const int sec = bn0 >> 10;   // 0=Q 1=K 2=V, uniform per block
#pragma unroll
  for (int i = 0; i < 4; ++i)
#pragma unroll
    for (int j = 0; j < 4; ++j) {
      const int col = bn0 + wn + j * 16 + l15;
      const float bs = bias[col];
      const int c2 = col & 1023, hh = c2 >> 6, dd = c2 & 63;
      const int rowb = bm0 + wm + i * 16 + lg * 4;
      const int bb = rowb >> 11, t0 = rowb & 2047;
      const int bh = bb * 16 + hh;
      if (sec < 2) {
        bf16* dst = (sec ? Kh : Qh) + ((size_t)bh * TT + t0) * HDIM + dd;
#pragma unroll
        for (int r = 0; r < 4; ++r) dst[(size_t)r * HDIM] = (bf16)(acc[i][j][r] + bs);
      } else {
        bf16x4 o4;
#pragma unroll
        for (int r = 0; r < 4; ++r) o4[r] = (bf16)(acc[i][j][r] + bs);
        *reinterpret_cast<bf16x4*>(VhT + ((size_t)bh * HDIM + dd) * TT + t0) = o4;
      }
    }
}

// ---------------- GEMM2: out = A @ W^T + b (fp32 out) ----------------
__global__ __launch_bounds__(256) void gemm_bt(const bf16* __restrict__ A,
                                               const bf16* __restrict__ W,
                                               const float* __restrict__ bias,
                                               float* __restrict__ Cf,
                                               int M, int N, int K) {
  const int tid  = threadIdx.x;
  const int lane = tid & 63, wave = tid >> 6;
  const int wm   = (wave >> 1) * 64;
  const int wn   = (wave & 1) * 64;
  const int bn0  = blockIdx.x * 128;
  const int bm0  = blockIdx.y * 128;
  const int l15  = lane & 15, lg = lane >> 4;

  f32x4 acc[4][4] = {};
  gemm_core(A, W, K, bm0, bn0, wm, wn, l15, lg, acc);

#pragma unroll
  for (int i = 0; i < 4; ++i)
#pragma unroll
    for (int j = 0; j < 4; ++j) {
      int col = bn0 + wn + j * 16 + l15;
      float bs = bias[col];
#pragma unroll
      for (int r = 0; r < 4; ++r) {
        int row = bm0 + wm + i * 16 + lg * 4 + r;
        Cf[(size_t)row * N + col] = acc[i][j][r] + bs;
      }
    }
}

// ---------------- softmax + pack for one 32q x 32kv S^T block ----------------
__device__ __forceinline__ void sm_pack(f32x16& s, float& mrun, float& srun,
                                        f32x16 (&oacc)[2], upw (&pw)[2],
                                        const int kv0, const int q0w,
                                        const int l31, const int hi) {
  // causal mask (diagonal-crossing tiles only)
  if (kv0 + 31 > q0w) {
    const int qg = q0w + l31;
#pragma unroll
    for (int r = 0; r < 16; ++r) {
      const int kvb = kv0 + (r & 3) + 8 * (r >> 2) + 4 * hi;
      if (kvb > qg) s[r] = -3e38f;
    }
  }
  // row max (q = l31): in-lane tree + one xor-32 exchange
  float m8[8];
#pragma unroll
  for (int i = 0; i < 8; ++i) m8[i] = fmaxf(s[i], s[i + 8]);
#pragma unroll
  for (int st = 4; st > 0; st >>= 1)
#pragma unroll
    for (int i = 0; i < st; ++i) m8[i] = fmaxf(m8[i], m8[i + st]);
  const float mx = fmaxf(m8[0], __shfl_xor(m8[0], 32));
  // defer-max (T13)
  float mref = mrun;
  if (!__all(mx <= mrun + 8.0f)) {
    const float mnew = fmaxf(mrun, mx);
    const float corr = __builtin_amdgcn_exp2f(mrun - mnew);
    mrun = mnew; mref = mnew;
    srun *= corr;
#pragma unroll
    for (int r = 0; r < 16; ++r) { oacc[0][r] *= corr; oacc[1][r] *= corr; }
  }
  float psum = 0.0f;
#pragma unroll
  for (int r = 0; r < 16; ++r) {
    s[r] = __builtin_amdgcn_exp2f(s[r] - mref);
    psum += s[r];
  }
  srun += psum;
  // P -> B-frag via pack + permlane32_swap (T12)
#pragma unroll
  for (int cl = 0; cl < 2; ++cl) {
    u32 a01 = pkbf(s[8 * cl + 0], s[8 * cl + 1]);
    u32 a23 = pkbf(s[8 * cl + 2], s[8 * cl + 3]);
    u32 b01 = pkbf(s[8 * cl + 4], s[8 * cl + 5]);
    u32 b23 = pkbf(s[8 * cl + 6], s[8 * cl + 7]);
    asm("v_permlane32_swap_b32 %0, %1" : "+v"(a01), "+v"(b01));
    asm("v_permlane32_swap_b32 %0, %1" : "+v"(a23), "+v"(b23));
    pw[cl].w[0] = a01; pw[cl].w[1] = a23; pw[cl].w[2] = b01; pw[cl].w[3] = b23;
  }
}

// ---------------- causal flash attention: LDS-free, dual-band, KVBLK=32 ----------
// block = (bh, pair p): 4 waves; wave owns 32 q of band H (qt=15-p) AND 32 of L (qt=p).
// All operands direct from global (L1/L2-resident); no LDS, no barriers.
__global__ __launch_bounds__(256, 2) void attn_kernel(const bf16* __restrict__ Qh,
                                                      const bf16* __restrict__ Kh,
                                                      const bf16* __restrict__ VhT,
                                                      bf16* __restrict__ aout) {
  const int tid  = threadIdx.x;
  const int lane = tid & 63, wave = tid >> 6;
  const int l31  = lane & 31;
  const int hi   = lane >> 5;
  const int bid  = blockIdx.x;              // 0..511
  const int bh   = bid & 63;
  const int p    = bid >> 6;                // 0..7
  const int qtH  = 15 - p, qtL = p;
  const int b    = bh >> 4, h = bh & 15;
  const int q0H  = qtH * 128 + wave * 32;
  const int q0L  = qtL * 128 + wave * 32;
  const size_t tb = (size_t)b * TT;

  const bf16* Kbh = Kh + (size_t)bh * TT * HDIM;
  const bf16* Vbh = VhT + (size_t)bh * HDIM * TT;

  // Q fragments for both bands, pre-scaled by 0.125*log2(e)
  const float QSCALE = 0.18033688011112042f;
  bf16x8 qfrH[4], qfrL[4];
  {
    const bf16* qrowH = Qh + ((size_t)bh * TT + q0H + l31) * HDIM;
    const bf16* qrowL = Qh + ((size_t)bh * TT + q0L + l31) * HDIM;
#pragma unroll
    for (int dc = 0; dc < 4; ++dc) {
      bf16x8 vH = *reinterpret_cast<const bf16x8*>(qrowH + dc * 16 + hi * 8);
      bf16x8 vL = *reinterpret_cast<const bf16x8*>(qrowL + dc * 16 + hi * 8);
      bf16x8 oH, oL;
#pragma unroll
      for (int j = 0; j < 8; ++j) {
        oH[j] = (bf16)((float)vH[j] * QSCALE);
        oL[j] = (bf16)((float)vL[j] * QSCALE);
      }
      qfrH[dc] = oH; qfrL[dc] = oL;
    }
  }

  f32x16 oaccH[2] = {}, oaccL[2] = {};
  float mH = -3e38f, sHr = 0.0f, mL = -3e38f, sLr = 0.0f;

  const int nkvH = (q0H >> 5) + 1;
  const int nkvL = (q0L >> 5) + 1;

  for (int t = 0; t < nkvH; ++t) {
    const int kv0 = t * 32;
    const bool doL = (t < nkvL);

    // K fragments (shared by both bands) + V fragments, direct from global
    bf16x8 kf[4];
#pragma unroll
    for (int dc = 0; dc < 4; ++dc)
      kf[dc] = *reinterpret_cast<const bf16x8*>(
          Kbh + (size_t)(kv0 + l31) * HDIM + dc * 16 + hi * 8);
    bf16x8 vf[2][2];
#pragma unroll
    for (int dh = 0; dh < 2; ++dh)
#pragma unroll
      for (int c = 0; c < 2; ++c)
        vf[dh][c] = *reinterpret_cast<const bf16x8*>(
            Vbh + (size_t)(32 * dh + l31) * TT + kv0 + c * 16 + hi * 8);

    // ---- QK^T band H: lane holds S[q=l31][kv=(r&3)+8(r>>2)+4hi]
    f32x16 sH = {};
    __builtin_amdgcn_s_setprio(1);
#pragma unroll
    for (int dc = 0; dc < 4; ++dc)
      sH = __builtin_amdgcn_mfma_f32_32x32x16_bf16(kf[dc], qfrH[dc], sH, 0, 0, 0);
    __builtin_amdgcn_s_setprio(0);
    upw pwH[2];
    sm_pack(sH, mH, sHr, oaccH, pwH, kv0, q0H, l31, hi);

    // ---- QK^T band L (shares kf)
    upw pwL[2];
    if (doL) {
      f32x16 sL = {};
      __builtin_amdgcn_s_setprio(1);
#pragma unroll
      for (int dc = 0; dc < 4; ++dc)
        sL = __builtin_amdgcn_mfma_f32_32x32x16_bf16(kf[dc], qfrL[dc], sL, 0, 0, 0);
      __builtin_amdgcn_s_setprio(0);
      sm_pack(sL, mL, sLr, oaccL, pwL, kv0, q0L, l31, hi);
    }

    // ---- PV both bands (share vf)
    __builtin_amdgcn_s_setprio(1);
#pragma unroll
    for (int dh = 0; dh < 2; ++dh)
#pragma unroll
      for (int c = 0; c < 2; ++c)
        oaccH[dh] = __builtin_amdgcn_mfma_f32_32x32x16_bf16(vf[dh][c], pwH[c].v,
                                                            oaccH[dh], 0, 0, 0);
    if (doL) {
#pragma unroll
      for (int dh = 0; dh < 2; ++dh)
#pragma unroll
        for (int c = 0; c < 2; ++c)
          oaccL[dh] = __builtin_amdgcn_mfma_f32_32x32x16_bf16(vf[dh][c], pwL[c].v,
                                                              oaccL[dh], 0, 0, 0);
    }
    __builtin_amdgcn_s_setprio(0);
  }

  // ---- epilogue: cross-lane rowsum, divide, store (both bands)
#pragma unroll
  for (int band = 0; band < 2; ++band) {
    const f32x16* oacc = band ? oaccL : oaccH;
    float sr = band ? sLr : sHr;
    sr += __shfl_xor(sr, 32);
    const float inv = 1.0f / sr;
    const int q = (band ? q0L : q0H) + l31;
    bf16* orow = aout + (tb + q) * (size_t)EMBED + h * HDIM;
#pragma unroll
    for (int dh = 0; dh < 2; ++dh)
#pragma unroll
      for (int rb = 0; rb < 4; ++rb) {
        bf16x4 o4;
#pragma unroll
        for (int k = 0; k < 4; ++k) o4[k] = (bf16)(oacc[dh][4 * rb + k] * inv);
        *reinterpret_cast<bf16x4*>(orow + 32 * dh + 8 * rb + 4 * hi) = o4;
      }
  }
}

extern "C" void kernel_launch(void* const* d_in, const int* in_sizes, int n_in,
                              void* d_out, int out_size, void* d_ws, size_t ws_size,
                              hipStream_t stream) {
  const float* x      = (const float*)d_in[0];
  const float* qkv_w  = (const float*)d_in[1];
  const float* qkv_b  = (const float*)d_in[2];
  const float* proj_w = (const float*)d_in[3];
  const float* proj_b = (const float*)d_in[4];
  float* out = (float*)d_out;

  const size_t QSZ = (size_t)BB * NHEAD * TT * HDIM;   // 8,388,608 elems per tensor
  char* ws = (char*)d_ws;
  bf16* xb    = (bf16*)ws;
  bf16* wqkv  = xb + (size_t)MTOK * EMBED;
  bf16* wproj = wqkv + (size_t)C3 * EMBED;
  bf16* Qh    = wproj + (size_t)EMBED * EMBED;
  bf16* Kh    = Qh + QSZ;
  bf16* VhT   = Kh + QSZ;
  bf16* aob   = xb;   // alias: xb dead after gemm_qkv

  cvt_kernel<<<dim3((MTOK * EMBED / 4 + 255) / 256), dim3(256), 0, stream>>>(x, xb, MTOK * EMBED);
  cvt_kernel<<<dim3((C3 * EMBED / 4 + 255) / 256), dim3(256), 0, stream>>>(qkv_w, wqkv, C3 * EMBED);
  cvt_kernel<<<dim3((EMBED * EMBED / 4 + 255) / 256), dim3(256), 0, stream>>>(proj_w, wproj, EMBED * EMBED);

  gemm_qkv<<<dim3(C3 / 128, MTOK / 128), dim3(256), 0, stream>>>(xb, wqkv, qkv_b, Qh, Kh, VhT);

  attn_kernel<<<dim3(512), dim3(256), 0, stream>>>(Qh, Kh, VhT, aob);

  gemm_bt<<<dim3(EMBED / 128, MTOK / 128), dim3(256), 0, stream>>>(
      aob, wproj, proj_b, out, MTOK, EMBED, EMBED);
}

// Round 8
// 174.748 us; speedup vs baseline: 1.2352x; 1.2352x over previous
//
#include <hip/hip_runtime.h>

#define EMBED 1024
#define C3    3072
#define NHEAD 16
#define HDIM  64
#define BB    4
#define TT    2048
#define MTOK  8192   // BB*TT

typedef __bf16 bf16;
typedef __bf16 bf16x4 __attribute__((ext_vector_type(4)));
typedef __bf16 bf16x8 __attribute__((ext_vector_type(8)));
typedef float  f32x4  __attribute__((ext_vector_type(4)));
typedef float  f32x16 __attribute__((ext_vector_type(16)));
typedef unsigned int u32;

__device__ __forceinline__ void gload_lds16(const bf16* g, bf16* l) {
  __builtin_amdgcn_global_load_lds((__attribute__((address_space(1))) void*)g,
                                   (__attribute__((address_space(3))) void*)l,
                                   16, 0, 0);
}

__device__ __forceinline__ u32 pkbf(float lo, float hi_) {
  union { bf16 h[2]; u32 w; } u;
  u.h[0] = (bf16)lo; u.h[1] = (bf16)hi_;
  return u.w;
}

union upw { u32 w[4]; bf16x8 v; };

// ---------------- fp32 -> bf16 convert ----------------
__global__ __launch_bounds__(256) void cvt_kernel(const float* __restrict__ in,
                                                  bf16* __restrict__ out, int n) {
  int i = (blockIdx.x * blockDim.x + threadIdx.x) * 4;
  if (i >= n) return;
  float4 v = *reinterpret_cast<const float4*>(in + i);
  bf16x4 o;
  o[0] = (bf16)v.x; o[1] = (bf16)v.y; o[2] = (bf16)v.z; o[3] = (bf16)v.w;
  *reinterpret_cast<bf16x4*>(out + i) = o;
}

// ================= GEMM core (BK=64, swizzled LDS) =================
// lA/lB: [128 rows][64 k], 16B-chunk XOR swizzle: chunk c of row stored at c^(row&7).
__device__ __forceinline__ void gemm_core(const bf16* __restrict__ A,
                                          const bf16* __restrict__ W,
                                          int K, int bm0, int bn0,
                                          int wm, int wn, int l15, int lg,
                                          f32x4 (&acc)[4][4]) {
  __shared__ __align__(16) bf16 lA[128 * 64];
  __shared__ __align__(16) bf16 lB[128 * 64];
  const int tid  = threadIdx.x;
  const int grow = tid >> 3;
  const int gseg = tid & 7;

  for (int kt = 0; kt < K; kt += 64) {
#pragma unroll
    for (int r = 0; r < 4; ++r) {
      const int row = r * 32 + grow;
      const int seg = gseg ^ (row & 7);
      gload_lds16(A + (size_t)(bm0 + row) * K + kt + seg * 8, &lA[(r * 256 + tid) * 8]);
      gload_lds16(W + (size_t)(bn0 + row) * K + kt + seg * 8, &lB[(r * 256 + tid) * 8]);
    }
    __syncthreads();
    const char* Ab = (const char*)lA;
    const char* Bb = (const char*)lB;
#pragma unroll
    for (int kk = 0; kk < 2; ++kk) {
      bf16x8 af[4], bf_[4];
#pragma unroll
      for (int i = 0; i < 4; ++i) {
        const int row = wm + i * 16 + l15;
        af[i] = *reinterpret_cast<const bf16x8*>(
            Ab + row * 128 + ((kk * 64 + lg * 16) ^ ((row & 7) << 4)));
      }
#pragma unroll
      for (int j = 0; j < 4; ++j) {
        const int row = wn + j * 16 + l15;
        bf_[j] = *reinterpret_cast<const bf16x8*>(
            Bb + row * 128 + ((kk * 64 + lg * 16) ^ ((row & 7) << 4)));
      }
#pragma unroll
      for (int i = 0; i < 4; ++i)
#pragma unroll
        for (int j = 0; j < 4; ++j)
          acc[i][j] = __builtin_amdgcn_mfma_f32_16x16x32_bf16(af[i], bf_[j],
                                                              acc[i][j], 0, 0, 0);
    }
    __syncthreads();
  }
}

// ---------------- GEMM1: qkv = x @ qkv_w^T + b, split into per-head layouts --------
__global__ __launch_bounds__(256) void gemm_qkv(const bf16* __restrict__ A,   // [8192][1024]
                                                const bf16* __restrict__ W,   // [3072][1024]
                                                const float* __restrict__ bias,
                                                bf16* __restrict__ Qh,
                                                bf16* __restrict__ Kh,
                                                bf16* __restrict__ VhT) {
  const int tid  = threadIdx.x;
  const int lane = tid & 63, wave = tid >> 6;
  const int wm   = (wave >> 1) * 64;
  const int wn   = (wave & 1) * 64;
  const int bn0  = blockIdx.x * 128;
  const int bm0  = blockIdx.y * 128;
  const int l15  = lane & 15, lg = lane >> 4;

  f32x4 acc[4][4] = {};
  gemm_core(A, W, EMBED, bm0, bn0, wm, wn, l15, lg, acc);

  const int sec = bn0 >> 10;   // 0=Q 1=K 2=V, uniform per block
#pragma unroll
  for (int i = 0; i < 4; ++i)
#pragma unroll
    for (int j = 0; j < 4; ++j) {
      const int col = bn0 + wn + j * 16 + l15;
      const float bs = bias[col];
      const int c2 = col & 1023, hh = c2 >> 6, dd = c2 & 63;
      const int rowb = bm0 + wm + i * 16 + lg * 4;
      const int bb = rowb >> 11, t0 = rowb & 2047;
      const int bh = bb * 16 + hh;
      if (sec < 2) {
        bf16* dst = (sec ? Kh : Qh) + ((size_t)bh * TT + t0) * HDIM + dd;
#pragma unroll
        for (int r = 0; r < 4; ++r) dst[(size_t)r * HDIM] = (bf16)(acc[i][j][r] + bs);
      } else {
        bf16x4 o4;
#pragma unroll
        for (int r = 0; r < 4; ++r) o4[r] = (bf16)(acc[i][j][r] + bs);
        *reinterpret_cast<bf16x4*>(VhT + ((size_t)bh * HDIM + dd) * TT + t0) = o4;
      }
    }
}

// ---------------- GEMM2: out = A @ W^T + b (fp32 out) ----------------
__global__ __launch_bounds__(256) void gemm_bt(const bf16* __restrict__ A,
                                               const bf16* __restrict__ W,
                                               const float* __restrict__ bias,
                                               float* __restrict__ Cf,
                                               int M, int N, int K) {
  const int tid  = threadIdx.x;
  const int lane = tid & 63, wave = tid >> 6;
  const int wm   = (wave >> 1) * 64;
  const int wn   = (wave & 1) * 64;
  const int bn0  = blockIdx.x * 128;
  const int bm0  = blockIdx.y * 128;
  const int l15  = lane & 15, lg = lane >> 4;

  f32x4 acc[4][4] = {};
  gemm_core(A, W, K, bm0, bn0, wm, wn, l15, lg, acc);

#pragma unroll
  for (int i = 0; i < 4; ++i)
#pragma unroll
    for (int j = 0; j < 4; ++j) {
      int col = bn0 + wn + j * 16 + l15;
      float bs = bias[col];
#pragma unroll
      for (int r = 0; r < 4; ++r) {
        int row = bm0 + wm + i * 16 + lg * 4 + r;
        Cf[(size_t)row * N + col] = acc[i][j][r] + bs;
      }
    }
}

// ---------------- one 32q x 64kv attention tile for one band ----------------
__device__ __forceinline__ void attn_tile(const char* kbase, const char* vbase,
                                          const bf16x8 (&qfr)[4], f32x16 (&oacc)[2],
                                          float& mrun, float& srun,
                                          const int kv0, const int q0w,
                                          const int l31, const int hi, const int swz) {
  // ---- QK^T: lane holds S[q=l31][kv = (r&3)+8(r>>2)+4hi (+32 for s1)]
  f32x16 s0 = {}, s1 = {};
  __builtin_amdgcn_s_setprio(1);
#pragma unroll
  for (int dc = 0; dc < 4; ++dc) {
    bf16x8 kf = *reinterpret_cast<const bf16x8*>(
        kbase + l31 * 128 + (((2 * dc + hi) * 16) ^ swz));
    s0 = __builtin_amdgcn_mfma_f32_32x32x16_bf16(kf, qfr[dc], s0, 0, 0, 0);
  }
#pragma unroll
  for (int dc = 0; dc < 4; ++dc) {
    bf16x8 kf = *reinterpret_cast<const bf16x8*>(
        kbase + (32 + l31) * 128 + (((2 * dc + hi) * 16) ^ swz));
    s1 = __builtin_amdgcn_mfma_f32_32x32x16_bf16(kf, qfr[dc], s1, 0, 0, 0);
  }
  __builtin_amdgcn_s_setprio(0);

  // ---- causal mask (diagonal-crossing tiles only)
  if (kv0 + 63 > q0w) {
    const int qg = q0w + l31;
#pragma unroll
    for (int r = 0; r < 16; ++r) {
      const int kvb = kv0 + (r & 3) + 8 * (r >> 2) + 4 * hi;
      if (kvb > qg)      s0[r] = -3e38f;
      if (kvb + 32 > qg) s1[r] = -3e38f;
    }
  }

  // ---- row max (q = l31): in-lane tree + one xor-32 exchange
  float m8[8];
#pragma unroll
  for (int i = 0; i < 8; ++i)
    m8[i] = fmaxf(fmaxf(s0[i], s0[i + 8]), fmaxf(s1[i], s1[i + 8]));
#pragma unroll
  for (int st = 4; st > 0; st >>= 1)
#pragma unroll
    for (int i = 0; i < st; ++i) m8[i] = fmaxf(m8[i], m8[i + st]);
  float mx = fmaxf(m8[0], __shfl_xor(m8[0], 32));

  // ---- defer-max (T13): only rescale when the tile max grew materially
  float mref = mrun;
  if (!__all(mx <= mrun + 8.0f)) {
    const float mnew = fmaxf(mrun, mx);
    const float corr = __builtin_amdgcn_exp2f(mrun - mnew);
    mrun = mnew; mref = mnew;
    srun *= corr;
#pragma unroll
    for (int r = 0; r < 16; ++r) { oacc[0][r] *= corr; oacc[1][r] *= corr; }
  }

  // ---- exp2 + partial rowsum (cross-lane sum deferred to epilogue)
  float psum = 0.0f;
#pragma unroll
  for (int r = 0; r < 16; ++r) {
    s0[r] = __builtin_amdgcn_exp2f(s0[r] - mref);
    s1[r] = __builtin_amdgcn_exp2f(s1[r] - mref);
    psum += s0[r] + s1[r];
  }
  srun += psum;

  // ---- P -> B-frag via pack + permlane32_swap (T12)
  upw pw[4];
#pragma unroll
  for (int cl = 0; cl < 2; ++cl) {
    {
      u32 a01 = pkbf(s0[8 * cl + 0], s0[8 * cl + 1]);
      u32 a23 = pkbf(s0[8 * cl + 2], s0[8 * cl + 3]);
      u32 b01 = pkbf(s0[8 * cl + 4], s0[8 * cl + 5]);
      u32 b23 = pkbf(s0[8 * cl + 6], s0[8 * cl + 7]);
      asm("v_permlane32_swap_b32 %0, %1" : "+v"(a01), "+v"(b01));
      asm("v_permlane32_swap_b32 %0, %1" : "+v"(a23), "+v"(b23));
      pw[cl].w[0] = a01; pw[cl].w[1] = a23; pw[cl].w[2] = b01; pw[cl].w[3] = b23;
    }
    {
      u32 a01 = pkbf(s1[8 * cl + 0], s1[8 * cl + 1]);
      u32 a23 = pkbf(s1[8 * cl + 2], s1[8 * cl + 3]);
      u32 b01 = pkbf(s1[8 * cl + 4], s1[8 * cl + 5]);
      u32 b23 = pkbf(s1[8 * cl + 6], s1[8 * cl + 7]);
      asm("v_permlane32_swap_b32 %0, %1" : "+v"(a01), "+v"(b01));
      asm("v_permlane32_swap_b32 %0, %1" : "+v"(a23), "+v"(b23));
      pw[2 + cl].w[0] = a01; pw[2 + cl].w[1] = a23; pw[2 + cl].w[2] = b01; pw[2 + cl].w[3] = b23;
    }
  }

  // ---- PV: O^T += V^T-frag x P-frag
  __builtin_amdgcn_s_setprio(1);
#pragma unroll
  for (int dh = 0; dh < 2; ++dh) {
    const char* vrow = vbase + (32 * dh + l31) * 128;
#pragma unroll
    for (int c = 0; c < 4; ++c) {
      bf16x8 vf = *reinterpret_cast<const bf16x8*>(vrow + (((2 * c + hi) * 16) ^ swz));
      oacc[dh] = __builtin_amdgcn_mfma_f32_32x32x16_bf16(vf, pw[c].v, oacc[dh], 0, 0, 0);
    }
  }
  __builtin_amdgcn_s_setprio(0);
}

// ---------------- causal flash attention: paired q-bands, shared KV stream ----------
// block = (bh, pair p): bands qt=15-p (H) and qt=p (L); 4 waves x 32 q rows per band.
__global__ __launch_bounds__(256, 2) void attn_kernel(const bf16* __restrict__ Qh,
                                                      const bf16* __restrict__ Kh,
                                                      const bf16* __restrict__ VhT,
                                                      bf16* __restrict__ aout) {
  __shared__ __align__(16) bf16 lK[2][64 * 64];
  __shared__ __align__(16) bf16 lVT[2][64 * 64];
  const int tid  = threadIdx.x;
  const int lane = tid & 63, wave = tid >> 6;
  const int l31  = lane & 31;
  const int hi   = lane >> 5;
  const int bid  = blockIdx.x;              // 0..511, linear: same-bh blocks land on one XCD
  const int bh   = bid & 63;
  const int p    = bid >> 6;                // 0..7
  const int qtH  = 15 - p, qtL = p;
  const int b    = bh >> 4, h = bh & 15;
  const int q0H  = qtH * 128 + wave * 32;
  const int q0L  = qtL * 128 + wave * 32;
  const size_t tb = (size_t)b * TT;
  const int swz  = (l31 & 7) << 4;

  // Q fragments for both bands, pre-scaled by 0.125*log2(e)
  const float QSCALE = 0.18033688011112042f;
  bf16x8 qfrH[4], qfrL[4];
  {
    const bf16* qrowH = Qh + ((size_t)bh * TT + q0H + l31) * HDIM;
    const bf16* qrowL = Qh + ((size_t)bh * TT + q0L + l31) * HDIM;
#pragma unroll
    for (int dc = 0; dc < 4; ++dc) {
      bf16x8 vH = *reinterpret_cast<const bf16x8*>(qrowH + dc * 16 + hi * 8);
      bf16x8 vL = *reinterpret_cast<const bf16x8*>(qrowL + dc * 16 + hi * 8);
      bf16x8 oH, oL;
#pragma unroll
      for (int j = 0; j < 8; ++j) {
        oH[j] = (bf16)((float)vH[j] * QSCALE);
        oL[j] = (bf16)((float)vL[j] * QSCALE);
      }
      qfrH[dc] = oH; qfrL[dc] = oL;
    }
  }

  f32x16 oaccH[2] = {}, oaccL[2] = {};
  float mH = -3e38f, sH = 0.0f, mL = -3e38f, sL = 0.0f;

  // staging (thread handles chunks tid and tid+256 of the 64x64 tiles)
  const int r0 = tid >> 3, sg = tid & 7;
  const bf16* kS0 = Kh + ((size_t)bh * TT + r0) * HDIM + (size_t)(sg ^ (r0 & 7)) * 8;
  const bf16* kS1 = Kh + ((size_t)bh * TT + 32 + r0) * HDIM + (size_t)(sg ^ (r0 & 7)) * 8;
  const bf16* vS0 = VhT + ((size_t)bh * HDIM + r0) * TT + (size_t)(sg ^ (r0 & 7)) * 8;
  const bf16* vS1 = VhT + ((size_t)bh * HDIM + 32 + r0) * TT + (size_t)(sg ^ (r0 & 7)) * 8;

  const int nkv = 2 * qtH + 2;

  // prologue: stage tile 0 into buf 0
  gload_lds16(kS0, &lK[0][tid * 8]);
  gload_lds16(kS1, &lK[0][(tid + 256) * 8]);
  gload_lds16(vS0, &lVT[0][tid * 8]);
  gload_lds16(vS1, &lVT[0][(tid + 256) * 8]);
  __syncthreads();

  int cur = 0;
  for (int t = 0; t < nkv; ++t) {
    const int kv0 = t * 64;
    if (t + 1 < nkv) {
      const int kvn = kv0 + 64;
      gload_lds16(kS0 + (size_t)kvn * HDIM, &lK[cur ^ 1][tid * 8]);
      gload_lds16(kS1 + (size_t)kvn * HDIM, &lK[cur ^ 1][(tid + 256) * 8]);
      gload_lds16(vS0 + kvn, &lVT[cur ^ 1][tid * 8]);
      gload_lds16(vS1 + kvn, &lVT[cur ^ 1][(tid + 256) * 8]);
    }

    const char* kbase = (const char*)&lK[cur][0];
    const char* vbase = (const char*)&lVT[cur][0];
    if (kv0 <= q0H + 31)
      attn_tile(kbase, vbase, qfrH, oaccH, mH, sH, kv0, q0H, l31, hi, swz);
    if (kv0 <= q0L + 31)
      attn_tile(kbase, vbase, qfrL, oaccL, mL, sL, kv0, q0L, l31, hi, swz);

    __syncthreads();   // drains prefetch + protects dbuf swap
    cur ^= 1;
  }

  // ---- epilogue: cross-lane rowsum, divide, store (both bands)
#pragma unroll
  for (int band = 0; band < 2; ++band) {
    const f32x16* oacc = band ? oaccL : oaccH;
    float sr = band ? sL : sH;
    sr += __shfl_xor(sr, 32);
    const float inv = 1.0f / sr;
    const int q = (band ? q0L : q0H) + l31;
    bf16* orow = aout + (tb + q) * (size_t)EMBED + h * HDIM;
#pragma unroll
    for (int dh = 0; dh < 2; ++dh)
#pragma unroll
      for (int rb = 0; rb < 4; ++rb) {
        bf16x4 o4;
#pragma unroll
        for (int k = 0; k < 4; ++k) o4[k] = (bf16)(oacc[dh][4 * rb + k] * inv);
        *reinterpret_cast<bf16x4*>(orow + 32 * dh + 8 * rb + 4 * hi) = o4;
      }
  }
}

extern "C" void kernel_launch(void* const* d_in, const int* in_sizes, int n_in,
                              void* d_out, int out_size, void* d_ws, size_t ws_size,
                              hipStream_t stream) {
  const float* x      = (const float*)d_in[0];
  const float* qkv_w  = (const float*)d_in[1];
  const float* qkv_b  = (const float*)d_in[2];
  const float* proj_w = (const float*)d_in[3];
  const float* proj_b = (const float*)d_in[4];
  float* out = (float*)d_out;

  const size_t QSZ = (size_t)BB * NHEAD * TT * HDIM;   // 8,388,608 elems per tensor
  char* ws = (char*)d_ws;
  bf16* xb    = (bf16*)ws;
  bf16* wqkv  = xb + (size_t)MTOK * EMBED;
  bf16* wproj = wqkv + (size_t)C3 * EMBED;
  bf16* Qh    = wproj + (size_t)EMBED * EMBED;
  bf16* Kh    = Qh + QSZ;
  bf16* VhT   = Kh + QSZ;
  bf16* aob   = xb;   // alias: xb dead after gemm_qkv

  cvt_kernel<<<dim3((MTOK * EMBED / 4 + 255) / 256), dim3(256), 0, stream>>>(x, xb, MTOK * EMBED);
  cvt_kernel<<<dim3((C3 * EMBED / 4 + 255) / 256), dim3(256), 0, stream>>>(qkv_w, wqkv, C3 * EMBED);
  cvt_kernel<<<dim3((EMBED * EMBED / 4 + 255) / 256), dim3(256), 0, stream>>>(proj_w, wproj, EMBED * EMBED);

  gemm_qkv<<<dim3(C3 / 128, MTOK / 128), dim3(256), 0, stream>>>(xb, wqkv, qkv_b, Qh, Kh, VhT);

  attn_kernel<<<dim3(512), dim3(256), 0, stream>>>(Qh, Kh, VhT, aob);

  gemm_bt<<<dim3(EMBED / 128, MTOK / 128), dim3(256), 0, stream>>>(
      aob, wproj, proj_b, out, MTOK, EMBED, EMBED);
}

// Round 9
// 173.737 us; speedup vs baseline: 1.2424x; 1.0058x over previous
//
#include <hip/hip_runtime.h>

#define EMBED 1024
#define C3    3072
#define NHEAD 16
#define HDIM  64
#define BB    4
#define TT    2048
#define MTOK  8192   // BB*TT

typedef __bf16 bf16;
typedef __bf16 bf16x4 __attribute__((ext_vector_type(4)));
typedef __bf16 bf16x8 __attribute__((ext_vector_type(8)));
typedef float  f32x4  __attribute__((ext_vector_type(4)));
typedef float  f32x16 __attribute__((ext_vector_type(16)));
typedef unsigned int u32;

__device__ __forceinline__ void gload_lds16(const bf16* g, bf16* l) {
  __builtin_amdgcn_global_load_lds((__attribute__((address_space(1))) void*)g,
                                   (__attribute__((address_space(3))) void*)l,
                                   16, 0, 0);
}

__device__ __forceinline__ u32 pkbf(float lo, float hi_) {
  union { bf16 h[2]; u32 w; } u;
  u.h[0] = (bf16)lo; u.h[1] = (bf16)hi_;
  return u.w;
}

__device__ __forceinline__ void wait_vm8()   { asm volatile("s_waitcnt vmcnt(8)" ::: "memory"); __builtin_amdgcn_sched_barrier(0); }
__device__ __forceinline__ void wait_vm0()   { asm volatile("s_waitcnt vmcnt(0)" ::: "memory"); __builtin_amdgcn_sched_barrier(0); }
__device__ __forceinline__ void wait_lgkm0() { asm volatile("s_waitcnt lgkmcnt(0)" ::: "memory"); __builtin_amdgcn_sched_barrier(0); }

union upw { u32 w[4]; bf16x8 v; };

// ---------------- fused fp32 -> bf16 convert (x, qkv_w, proj_w in one launch) -------
__global__ __launch_bounds__(256) void cvt_all(const float* __restrict__ x,
                                               const float* __restrict__ w1,
                                               const float* __restrict__ w2,
                                               bf16* __restrict__ xb,
                                               bf16* __restrict__ wqkv,
                                               bf16* __restrict__ wproj) {
  const int N1 = MTOK * EMBED, N2 = C3 * EMBED, N3 = EMBED * EMBED;
  int i = (blockIdx.x * blockDim.x + threadIdx.x) * 4;
  const float* src; bf16* dst;
  if (i < N1)           { src = x + i;            dst = xb + i; }
  else if (i < N1 + N2) { src = w1 + (i - N1);    dst = wqkv + (i - N1); }
  else if (i < N1 + N2 + N3) { src = w2 + (i - N1 - N2); dst = wproj + (i - N1 - N2); }
  else return;
  float4 v = *reinterpret_cast<const float4*>(src);
  bf16x4 o;
  o[0] = (bf16)v.x; o[1] = (bf16)v.y; o[2] = (bf16)v.z; o[3] = (bf16)v.w;
  *reinterpret_cast<bf16x4*>(dst) = o;
}

// ================= GEMM core (BK=64, swizzled LDS, hoisted addressing) =============
__device__ __forceinline__ void gemm_core(const bf16* __restrict__ A,
                                          const bf16* __restrict__ W,
                                          int K, int bm0, int bn0,
                                          int wm, int wn, int l15, int lg,
                                          f32x4 (&acc)[4][4]) {
  __shared__ __align__(16) bf16 lA[128 * 64];
  __shared__ __align__(16) bf16 lB[128 * 64];
  const int tid  = threadIdx.x;
  const int grow = tid >> 3;
  const int gseg = tid & 7;

  // hoisted staging source pointers (bump by 64 per k-step)
  const bf16* srcA[4];
  const bf16* srcB[4];
#pragma unroll
  for (int r = 0; r < 4; ++r) {
    const int row = r * 32 + grow;
    const int seg = gseg ^ (row & 7);
    srcA[r] = A + (size_t)(bm0 + row) * K + seg * 8;
    srcB[r] = W + (size_t)(bn0 + row) * K + seg * 8;
  }
  // hoisted fragment byte-offsets
  int offA[2][4], offB[2][4];
#pragma unroll
  for (int kk = 0; kk < 2; ++kk) {
#pragma unroll
    for (int i = 0; i < 4; ++i) {
      const int rowA = wm + i * 16 + l15;
      const int rowB = wn + i * 16 + l15;
      offA[kk][i] = rowA * 128 + ((kk * 64 + lg * 16) ^ ((rowA & 7) << 4));
      offB[kk][i] = rowB * 128 + ((kk * 64 + lg * 16) ^ ((rowB & 7) << 4));
    }
  }

  for (int kt = 0; kt < K; kt += 64) {
#pragma unroll
    for (int r = 0; r < 4; ++r) {
      gload_lds16(srcA[r] + kt, &lA[(r * 256 + tid) * 8]);
      gload_lds16(srcB[r] + kt, &lB[(r * 256 + tid) * 8]);
    }
    __syncthreads();
    const char* Ab = (const char*)lA;
    const char* Bb = (const char*)lB;
#pragma unroll
    for (int kk = 0; kk < 2; ++kk) {
      bf16x8 af[4], bf_[4];
#pragma unroll
      for (int i = 0; i < 4; ++i) af[i]  = *reinterpret_cast<const bf16x8*>(Ab + offA[kk][i]);
#pragma unroll
      for (int j = 0; j < 4; ++j) bf_[j] = *reinterpret_cast<const bf16x8*>(Bb + offB[kk][j]);
#pragma unroll
      for (int i = 0; i < 4; ++i)
#pragma unroll
        for (int j = 0; j < 4; ++j)
          acc[i][j] = __builtin_amdgcn_mfma_f32_16x16x32_bf16(af[i], bf_[j],
                                                              acc[i][j], 0, 0, 0);
    }
    __syncthreads();
  }
}

// ---------------- GEMM1: qkv = x @ qkv_w^T + b, split into per-head layouts --------
__global__ __launch_bounds__(256) void gemm_qkv(const bf16* __restrict__ A,
                                                const bf16* __restrict__ W,
                                                const float* __restrict__ bias,
                                                bf16* __restrict__ Qh,
                                                bf16* __restrict__ Kh,
                                                bf16* __restrict__ VhT) {
  const int tid  = threadIdx.x;
  const int lane = tid & 63, wave = tid >> 6;
  const int wm   = (wave >> 1) * 64;
  const int wn   = (wave & 1) * 64;
  const int bn0  = blockIdx.x * 128;
  const int bm0  = blockIdx.y * 128;
  const int l15  = lane & 15, lg = lane >> 4;

  f32x4 acc[4][4] = {};
  gemm_core(A, W, EMBED, bm0, bn0, wm, wn, l15, lg, acc);

  const int sec = bn0 >> 10;   // 0=Q 1=K 2=V, uniform per block
#pragma unroll
  for (int i = 0; i < 4; ++i)
#pragma unroll
    for (int j = 0; j < 4; ++j) {
      const int col = bn0 + wn + j * 16 + l15;
      const float bs = bias[col];
      const int c2 = col & 1023, hh = c2 >> 6, dd = c2 & 63;
      const int rowb = bm0 + wm + i * 16 + lg * 4;
      const int bb = rowb >> 11, t0 = rowb & 2047;
      const int bh = bb * 16 + hh;
      if (sec < 2) {
        bf16* dst = (sec ? Kh : Qh) + ((size_t)bh * TT + t0) * HDIM + dd;
#pragma unroll
        for (int r = 0; r < 4; ++r) dst[(size_t)r * HDIM] = (bf16)(acc[i][j][r] + bs);
      } else {
        bf16x4 o4;
#pragma unroll
        for (int r = 0; r < 4; ++r) o4[r] = (bf16)(acc[i][j][r] + bs);
        *reinterpret_cast<bf16x4*>(VhT + ((size_t)bh * HDIM + dd) * TT + t0) = o4;
      }
    }
}

// ---------------- GEMM2: out = A @ W^T + b (fp32 out) ----------------
__global__ __launch_bounds__(256) void gemm_bt(const bf16* __restrict__ A,
                                               const bf16* __restrict__ W,
                                               const float* __restrict__ bias,
                                               float* __restrict__ Cf,
                                               int M, int N, int K) {
  const int tid  = threadIdx.x;
  const int lane = tid & 63, wave = tid >> 6;
  const int wm   = (wave >> 1) * 64;
  const int wn   = (wave & 1) * 64;
  const int bn0  = blockIdx.x * 128;
  const int bm0  = blockIdx.y * 128;
  const int l15  = lane & 15, lg = lane >> 4;

  f32x4 acc[4][4] = {};
  gemm_core(A, W, K, bm0, bn0, wm, wn, l15, lg, acc);

#pragma unroll
  for (int i = 0; i < 4; ++i)
#pragma unroll
    for (int j = 0; j < 4; ++j) {
      int col = bn0 + wn + j * 16 + l15;
      float bs = bias[col];
#pragma unroll
      for (int r = 0; r < 4; ++r) {
        int row = bm0 + wm + i * 16 + lg * 4 + r;
        Cf[(size_t)row * N + col] = acc[i][j][r] + bs;
      }
    }
}

// ---------------- softmax + pack for one 32q x 32kv S^T block (verified r7) --------
__device__ __forceinline__ void sm_pack(f32x16& s, float& mrun, float& srun,
                                        f32x16 (&oacc)[2], upw (&pw)[2],
                                        const int kv0, const int q0w,
                                        const int l31, const int hi) {
  if (kv0 + 31 > q0w) {
    const int qg = q0w + l31;
#pragma unroll
    for (int r = 0; r < 16; ++r) {
      const int kvb = kv0 + (r & 3) + 8 * (r >> 2) + 4 * hi;
      if (kvb > qg) s[r] = -3e38f;
    }
  }
  float m8[8];
#pragma unroll
  for (int i = 0; i < 8; ++i) m8[i] = fmaxf(s[i], s[i + 8]);
#pragma unroll
  for (int st = 4; st > 0; st >>= 1)
#pragma unroll
    for (int i = 0; i < st; ++i) m8[i] = fmaxf(m8[i], m8[i + st]);
  const float mx = fmaxf(m8[0], __shfl_xor(m8[0], 32));
  float mref = mrun;
  if (!__all(mx <= mrun + 8.0f)) {
    const float mnew = fmaxf(mrun, mx);
    const float corr = __builtin_amdgcn_exp2f(mrun - mnew);
    mrun = mnew; mref = mnew;
    srun *= corr;
#pragma unroll
    for (int r = 0; r < 16; ++r) { oacc[0][r] *= corr; oacc[1][r] *= corr; }
  }
  float psum = 0.0f;
#pragma unroll
  for (int r = 0; r < 16; ++r) {
    s[r] = __builtin_amdgcn_exp2f(s[r] - mref);
    psum += s[r];
  }
  srun += psum;
#pragma unroll
  for (int cl = 0; cl < 2; ++cl) {
    u32 a01 = pkbf(s[8 * cl + 0], s[8 * cl + 1]);
    u32 a23 = pkbf(s[8 * cl + 2], s[8 * cl + 3]);
    u32 b01 = pkbf(s[8 * cl + 4], s[8 * cl + 5]);
    u32 b23 = pkbf(s[8 * cl + 6], s[8 * cl + 7]);
    asm("v_permlane32_swap_b32 %0, %1" : "+v"(a01), "+v"(b01));
    asm("v_permlane32_swap_b32 %0, %1" : "+v"(a23), "+v"(b23));
    pw[cl].w[0] = a01; pw[cl].w[1] = a23; pw[cl].w[2] = b01; pw[cl].w[3] = b23;
  }
}

// ---------------- per-wave KV tile staging (8 gload_lds, swizzled) -----------------
// K tile: [32 kv][64 d] rows 128B, chunk c at slot c^(row&7).
// V tile: [32 r][8 chunks] rows 128B; chunk g at dhalf-row r holds
//         V^T[d = r + 32*(g>>2)][kv0 + (g&3)*8 .. +8); stored at slot g^(r&7).
__device__ __forceinline__ void stage_kv(const bf16* __restrict__ Kbh,
                                         const bf16* __restrict__ Vbh,
                                         int kv0, bf16* kbase, bf16* vbase, int lane) {
  const int rsub = lane >> 3;           // row within 8-row group == row&7
  const int g    = (lane & 7) ^ rsub;   // global chunk this lane fetches
#pragma unroll
  for (int i = 0; i < 4; ++i) {
    const int row = 8 * i + rsub;
    gload_lds16(Kbh + (size_t)(kv0 + row) * HDIM + g * 8, kbase + i * 512);
  }
  const int d0 = rsub + 32 * (g >> 2);
  const int kc = (g & 3) * 8;
#pragma unroll
  for (int i = 0; i < 4; ++i) {
    gload_lds16(Vbh + (size_t)(8 * i + d0) * TT + kv0 + kc, vbase + i * 512);
  }
}

// ---------------- causal flash attention: barrier-free per-wave pipeline -----------
// block = (bh, pair p); each wave independently processes 32 q rows of band H
// (qt=15-p) and band L (qt=p) against its own staged KV stream (KVBLK=32, dbuf,
// counted vmcnt, no __syncthreads).
__global__ __launch_bounds__(256, 2) void attn_kernel(const bf16* __restrict__ Qh,
                                                      const bf16* __restrict__ Kh,
                                                      const bf16* __restrict__ VhT,
                                                      bf16* __restrict__ aout) {
  __shared__ __align__(16) bf16 lds[4][2][2][2048];   // [wave][buf][K/V][32x64]
  const int tid  = threadIdx.x;
  const int lane = tid & 63, wave = tid >> 6;
  const int l31  = lane & 31;
  const int hi   = lane >> 5;
  const int bid  = blockIdx.x;              // 0..511
  const int bh   = bid & 63;
  const int p    = bid >> 6;                // 0..7
  const int qtH  = 15 - p, qtL = p;
  const int b    = bh >> 4, h = bh & 15;
  const int q0H  = qtH * 128 + wave * 32;
  const int q0L  = qtL * 128 + wave * 32;
  const size_t tb = (size_t)b * TT;
  const int swz  = (l31 & 7) << 4;

  const bf16* Kbh = Kh + (size_t)bh * TT * HDIM;
  const bf16* Vbh = VhT + (size_t)bh * HDIM * TT;

  // Q fragments for both bands, pre-scaled by 0.125*log2(e)
  const float QSCALE = 0.18033688011112042f;
  bf16x8 qfrH[4], qfrL[4];
  {
    const bf16* qrowH = Qh + ((size_t)bh * TT + q0H + l31) * HDIM;
    const bf16* qrowL = Qh + ((size_t)bh * TT + q0L + l31) * HDIM;
#pragma unroll
    for (int dc = 0; dc < 4; ++dc) {
      bf16x8 vH = *reinterpret_cast<const bf16x8*>(qrowH + dc * 16 + hi * 8);
      bf16x8 vL = *reinterpret_cast<const bf16x8*>(qrowL + dc * 16 + hi * 8);
      bf16x8 oH, oL;
#pragma unroll
      for (int j = 0; j < 8; ++j) {
        oH[j] = (bf16)((float)vH[j] * QSCALE);
        oL[j] = (bf16)((float)vL[j] * QSCALE);
      }
      qfrH[dc] = oH; qfrL[dc] = oL;
    }
  }
  wait_vm0();   // drain Q loads so staging vmcnt ledger starts at 0

  f32x16 oaccH[2] = {}, oaccL[2] = {};
  float mH = -3e38f, sHr = 0.0f, mL = -3e38f, sLr = 0.0f;

  const int nkvH = 4 * qtH + wave + 1;   // (q0H>>5)+1, always >= 33
  const int nkvL = 4 * qtL + wave + 1;

  // prologue: stage tiles 0 and 1
  stage_kv(Kbh, Vbh, 0,  &lds[wave][0][0][0], &lds[wave][0][1][0], lane);
  stage_kv(Kbh, Vbh, 32, &lds[wave][1][0][0], &lds[wave][1][1][0], lane);

  for (int t = 0; t < nkvH; ++t) {
    if (t < nkvH - 1) wait_vm8(); else wait_vm0();   // tile t resident

    const char* kb = (const char*)&lds[wave][t & 1][0][0];
    const char* vb = (const char*)&lds[wave][t & 1][1][0];
    bf16x8 kf[4], vf[2][2];
#pragma unroll
    for (int dc = 0; dc < 4; ++dc)
      kf[dc] = *reinterpret_cast<const bf16x8*>(kb + l31 * 128 + (((2 * dc + hi) * 16) ^ swz));
#pragma unroll
    for (int dh = 0; dh < 2; ++dh)
#pragma unroll
      for (int c = 0; c < 2; ++c)
        vf[dh][c] = *reinterpret_cast<const bf16x8*>(
            vb + l31 * 128 + (((4 * dh + 2 * c + hi) * 16) ^ swz));
    wait_lgkm0();   // frags in regs; safe to overwrite this buffer

    if (t + 2 < nkvH)
      stage_kv(Kbh, Vbh, (t + 2) * 32,
               &lds[wave][t & 1][0][0], &lds[wave][t & 1][1][0], lane);

    const int kv0 = t * 32;
    // ---- band H
    f32x16 sH = {};
    __builtin_amdgcn_s_setprio(1);
#pragma unroll
    for (int dc = 0; dc < 4; ++dc)
      sH = __builtin_amdgcn_mfma_f32_32x32x16_bf16(kf[dc], qfrH[dc], sH, 0, 0, 0);
    __builtin_amdgcn_s_setprio(0);
    upw pwH[2];
    sm_pack(sH, mH, sHr, oaccH, pwH, kv0, q0H, l31, hi);

    // ---- band L (shares kf/vf)
    const bool doL = (t < nkvL);
    upw pwL[2];
    if (doL) {
      f32x16 sL = {};
      __builtin_amdgcn_s_setprio(1);
#pragma unroll
      for (int dc = 0; dc < 4; ++dc)
        sL = __builtin_amdgcn_mfma_f32_32x32x16_bf16(kf[dc], qfrL[dc], sL, 0, 0, 0);
      __builtin_amdgcn_s_setprio(0);
      sm_pack(sL, mL, sLr, oaccL, pwL, kv0, q0L, l31, hi);
    }

    // ---- PV both bands
    __builtin_amdgcn_s_setprio(1);
#pragma unroll
    for (int dh = 0; dh < 2; ++dh)
#pragma unroll
      for (int c = 0; c < 2; ++c)
        oaccH[dh] = __builtin_amdgcn_mfma_f32_32x32x16_bf16(vf[dh][c], pwH[c].v,
                                                            oaccH[dh], 0, 0, 0);
    if (doL) {
#pragma unroll
      for (int dh = 0; dh < 2; ++dh)
#pragma unroll
        for (int c = 0; c < 2; ++c)
          oaccL[dh] = __builtin_amdgcn_mfma_f32_32x32x16_bf16(vf[dh][c], pwL[c].v,
                                                              oaccL[dh], 0, 0, 0);
    }
    __builtin_amdgcn_s_setprio(0);
  }

  // ---- epilogue: cross-lane rowsum, divide, store (both bands)
#pragma unroll
  for (int band = 0; band < 2; ++band) {
    const f32x16* oacc = band ? oaccL : oaccH;
    float sr = band ? sLr : sHr;
    sr += __shfl_xor(sr, 32);
    const float inv = 1.0f / sr;
    const int q = (band ? q0L : q0H) + l31;
    bf16* orow = aout + (tb + q) * (size_t)EMBED + h * HDIM;
#pragma unroll
    for (int dh = 0; dh < 2; ++dh)
#pragma unroll
      for (int rb = 0; rb < 4; ++rb) {
        bf16x4 o4;
#pragma unroll
        for (int k = 0; k < 4; ++k) o4[k] = (bf16)(oacc[dh][4 * rb + k] * inv);
        *reinterpret_cast<bf16x4*>(orow + 32 * dh + 8 * rb + 4 * hi) = o4;
      }
  }
}

extern "C" void kernel_launch(void* const* d_in, const int* in_sizes, int n_in,
                              void* d_out, int out_size, void* d_ws, size_t ws_size,
                              hipStream_t stream) {
  const float* x      = (const float*)d_in[0];
  const float* qkv_w  = (const float*)d_in[1];
  const float* qkv_b  = (const float*)d_in[2];
  const float* proj_w = (const float*)d_in[3];
  const float* proj_b = (const float*)d_in[4];
  float* out = (float*)d_out;

  const size_t QSZ = (size_t)BB * NHEAD * TT * HDIM;   // 8,388,608 elems per tensor
  char* ws = (char*)d_ws;
  bf16* xb    = (bf16*)ws;
  bf16* wqkv  = xb + (size_t)MTOK * EMBED;
  bf16* wproj = wqkv + (size_t)C3 * EMBED;
  bf16* Qh    = wproj + (size_t)EMBED * EMBED;
  bf16* Kh    = Qh + QSZ;
  bf16* VhT   = Kh + QSZ;
  bf16* aob   = xb;   // alias: xb dead after gemm_qkv

  const int NCVT = (MTOK * EMBED + C3 * EMBED + EMBED * EMBED) / 4;
  cvt_all<<<dim3((NCVT + 255) / 256), dim3(256), 0, stream>>>(x, qkv_w, proj_w,
                                                              xb, wqkv, wproj);

  gemm_qkv<<<dim3(C3 / 128, MTOK / 128), dim3(256), 0, stream>>>(xb, wqkv, qkv_b, Qh, Kh, VhT);

  attn_kernel<<<dim3(512), dim3(256), 0, stream>>>(Qh, Kh, VhT, aob);

  gemm_bt<<<dim3(EMBED / 128, MTOK / 128), dim3(256), 0, stream>>>(
      aob, wproj, proj_b, out, MTOK, EMBED, EMBED);
}

// Round 10
// 165.713 us; speedup vs baseline: 1.3026x; 1.0484x over previous
//
#include <hip/hip_runtime.h>

#define EMBED 1024
#define C3    3072
#define NHEAD 16
#define HDIM  64
#define BB    4
#define TT    2048
#define MTOK  8192   // BB*TT

typedef __bf16 bf16;
typedef __bf16 bf16x4 __attribute__((ext_vector_type(4)));
typedef __bf16 bf16x8 __attribute__((ext_vector_type(8)));
typedef float  f32x4  __attribute__((ext_vector_type(4)));
typedef float  f32x16 __attribute__((ext_vector_type(16)));
typedef unsigned int u32;

__device__ __forceinline__ void gload_lds16(const bf16* g, bf16* l) {
  __builtin_amdgcn_global_load_lds((__attribute__((address_space(1))) void*)g,
                                   (__attribute__((address_space(3))) void*)l,
                                   16, 0, 0);
}

__device__ __forceinline__ u32 pkbf(float lo, float hi_) {
  union { bf16 h[2]; u32 w; } u;
  u.h[0] = (bf16)lo; u.h[1] = (bf16)hi_;
  return u.w;
}

union upw { u32 w[4]; bf16x8 v; };

// ---------------- fused fp32 -> bf16 convert (x, qkv_w, proj_w in one launch) -------
__global__ __launch_bounds__(256) void cvt_all(const float* __restrict__ x,
                                               const float* __restrict__ w1,
                                               const float* __restrict__ w2,
                                               bf16* __restrict__ xb,
                                               bf16* __restrict__ wqkv,
                                               bf16* __restrict__ wproj) {
  const int N1 = MTOK * EMBED, N2 = C3 * EMBED, N3 = EMBED * EMBED;
  int i = (blockIdx.x * blockDim.x + threadIdx.x) * 4;
  const float* src; bf16* dst;
  if (i < N1)           { src = x + i;            dst = xb + i; }
  else if (i < N1 + N2) { src = w1 + (i - N1);    dst = wqkv + (i - N1); }
  else if (i < N1 + N2 + N3) { src = w2 + (i - N1 - N2); dst = wproj + (i - N1 - N2); }
  else return;
  float4 v = *reinterpret_cast<const float4*>(src);
  bf16x4 o;
  o[0] = (bf16)v.x; o[1] = (bf16)v.y; o[2] = (bf16)v.z; o[3] = (bf16)v.w;
  *reinterpret_cast<bf16x4*>(dst) = o;
}

// ================= GEMM core (BK=64, swizzled LDS, hoisted addressing) =============
__device__ __forceinline__ void gemm_core(const bf16* __restrict__ A,
                                          const bf16* __restrict__ W,
                                          int K, int bm0, int bn0,
                                          int wm, int wn, int l15, int lg,
                                          f32x4 (&acc)[4][4]) {
  __shared__ __align__(16) bf16 lA[128 * 64];
  __shared__ __align__(16) bf16 lB[128 * 64];
  const int tid  = threadIdx.x;
  const int grow = tid >> 3;
  const int gseg = tid & 7;

  // hoisted staging source pointers (bump by kt per k-step)
  const bf16* srcA[4];
  const bf16* srcB[4];
#pragma unroll
  for (int r = 0; r < 4; ++r) {
    const int row = r * 32 + grow;
    const int seg = gseg ^ (row & 7);
    srcA[r] = A + (size_t)(bm0 + row) * K + seg * 8;
    srcB[r] = W + (size_t)(bn0 + row) * K + seg * 8;
  }
  // hoisted fragment byte-offsets
  int offA[2][4], offB[2][4];
#pragma unroll
  for (int kk = 0; kk < 2; ++kk) {
#pragma unroll
    for (int i = 0; i < 4; ++i) {
      const int rowA = wm + i * 16 + l15;
      const int rowB = wn + i * 16 + l15;
      offA[kk][i] = rowA * 128 + ((kk * 64 + lg * 16) ^ ((rowA & 7) << 4));
      offB[kk][i] = rowB * 128 + ((kk * 64 + lg * 16) ^ ((rowB & 7) << 4));
    }
  }

  for (int kt = 0; kt < K; kt += 64) {
#pragma unroll
    for (int r = 0; r < 4; ++r) {
      gload_lds16(srcA[r] + kt, &lA[(r * 256 + tid) * 8]);
      gload_lds16(srcB[r] + kt, &lB[(r * 256 + tid) * 8]);
    }
    __syncthreads();
    const char* Ab = (const char*)lA;
    const char* Bb = (const char*)lB;
#pragma unroll
    for (int kk = 0; kk < 2; ++kk) {
      bf16x8 af[4], bf_[4];
#pragma unroll
      for (int i = 0; i < 4; ++i) af[i]  = *reinterpret_cast<const bf16x8*>(Ab + offA[kk][i]);
#pragma unroll
      for (int j = 0; j < 4; ++j) bf_[j] = *reinterpret_cast<const bf16x8*>(Bb + offB[kk][j]);
#pragma unroll
      for (int i = 0; i < 4; ++i)
#pragma unroll
        for (int j = 0; j < 4; ++j)
          acc[i][j] = __builtin_amdgcn_mfma_f32_16x16x32_bf16(af[i], bf_[j],
                                                              acc[i][j], 0, 0, 0);
    }
    __syncthreads();
  }
}

// ---------------- GEMM1: qkv = x @ qkv_w^T + b, split into per-head layouts --------
__global__ __launch_bounds__(256) void gemm_qkv(const bf16* __restrict__ A,
                                                const bf16* __restrict__ W,
                                                const float* __restrict__ bias,
                                                bf16* __restrict__ Qh,
                                                bf16* __restrict__ Kh,
                                                bf16* __restrict__ VhT) {
  const int tid  = threadIdx.x;
  const int lane = tid & 63, wave = tid >> 6;
  const int wm   = (wave >> 1) * 64;
  const int wn   = (wave & 1) * 64;
  const int bn0  = blockIdx.x * 128;
  const int bm0  = blockIdx.y * 128;
  const int l15  = lane & 15, lg = lane >> 4;

  f32x4 acc[4][4] = {};
  gemm_core(A, W, EMBED, bm0, bn0, wm, wn, l15, lg, acc);

  const int sec = bn0 >> 10;   // 0=Q 1=K 2=V, uniform per block
#pragma unroll
  for (int i = 0; i < 4; ++i)
#pragma unroll
    for (int j = 0; j < 4; ++j) {
      const int col = bn0 + wn + j * 16 + l15;
      const float bs = bias[col];
      const int c2 = col & 1023, hh = c2 >> 6, dd = c2 & 63;
      const int rowb = bm0 + wm + i * 16 + lg * 4;
      const int bb = rowb >> 11, t0 = rowb & 2047;
      const int bh = bb * 16 + hh;
      if (sec < 2) {
        bf16* dst = (sec ? Kh : Qh) + ((size_t)bh * TT + t0) * HDIM + dd;
#pragma unroll
        for (int r = 0; r < 4; ++r) dst[(size_t)r * HDIM] = (bf16)(acc[i][j][r] + bs);
      } else {
        bf16x4 o4;
#pragma unroll
        for (int r = 0; r < 4; ++r) o4[r] = (bf16)(acc[i][j][r] + bs);
        *reinterpret_cast<bf16x4*>(VhT + ((size_t)bh * HDIM + dd) * TT + t0) = o4;
      }
    }
}

// ---------------- GEMM2: out = A @ W^T + b (fp32 out) ----------------
__global__ __launch_bounds__(256) void gemm_bt(const bf16* __restrict__ A,
                                               const bf16* __restrict__ W,
                                               const float* __restrict__ bias,
                                               float* __restrict__ Cf,
                                               int M, int N, int K) {
  const int tid  = threadIdx.x;
  const int lane = tid & 63, wave = tid >> 6;
  const int wm   = (wave >> 1) * 64;
  const int wn   = (wave & 1) * 64;
  const int bn0  = blockIdx.x * 128;
  const int bm0  = blockIdx.y * 128;
  const int l15  = lane & 15, lg = lane >> 4;

  f32x4 acc[4][4] = {};
  gemm_core(A, W, K, bm0, bn0, wm, wn, l15, lg, acc);

#pragma unroll
  for (int i = 0; i < 4; ++i)
#pragma unroll
    for (int j = 0; j < 4; ++j) {
      int col = bn0 + wn + j * 16 + l15;
      float bs = bias[col];
#pragma unroll
      for (int r = 0; r < 4; ++r) {
        int row = bm0 + wm + i * 16 + lg * 4 + r;
        Cf[(size_t)row * N + col] = acc[i][j][r] + bs;
      }
    }
}

// ---------------- one 32q x 64kv attention tile for one band ----------------
__device__ __forceinline__ void attn_tile(const char* kbase, const char* vbase,
                                          const bf16x8 (&qfr)[4], f32x16 (&oacc)[2],
                                          float& mrun, float& srun,
                                          const int kv0, const int q0w,
                                          const int l31, const int hi, const int swz) {
  // ---- QK^T: lane holds S[q=l31][kv = (r&3)+8(r>>2)+4hi (+32 for s1)]
  f32x16 s0 = {}, s1 = {};
  __builtin_amdgcn_s_setprio(1);
#pragma unroll
  for (int dc = 0; dc < 4; ++dc) {
    bf16x8 kf = *reinterpret_cast<const bf16x8*>(
        kbase + l31 * 128 + (((2 * dc + hi) * 16) ^ swz));
    s0 = __builtin_amdgcn_mfma_f32_32x32x16_bf16(kf, qfr[dc], s0, 0, 0, 0);
  }
#pragma unroll
  for (int dc = 0; dc < 4; ++dc) {
    bf16x8 kf = *reinterpret_cast<const bf16x8*>(
        kbase + (32 + l31) * 128 + (((2 * dc + hi) * 16) ^ swz));
    s1 = __builtin_amdgcn_mfma_f32_32x32x16_bf16(kf, qfr[dc], s1, 0, 0, 0);
  }
  __builtin_amdgcn_s_setprio(0);

  // ---- causal mask (diagonal-crossing tiles only)
  if (kv0 + 63 > q0w) {
    const int qg = q0w + l31;
#pragma unroll
    for (int r = 0; r < 16; ++r) {
      const int kvb = kv0 + (r & 3) + 8 * (r >> 2) + 4 * hi;
      if (kvb > qg)      s0[r] = -3e38f;
      if (kvb + 32 > qg) s1[r] = -3e38f;
    }
  }

  // ---- row max (q = l31): in-lane tree + one xor-32 exchange
  float m8[8];
#pragma unroll
  for (int i = 0; i < 8; ++i)
    m8[i] = fmaxf(fmaxf(s0[i], s0[i + 8]), fmaxf(s1[i], s1[i + 8]));
#pragma unroll
  for (int st = 4; st > 0; st >>= 1)
#pragma unroll
    for (int i = 0; i < st; ++i) m8[i] = fmaxf(m8[i], m8[i + st]);
  float mx = fmaxf(m8[0], __shfl_xor(m8[0], 32));

  // ---- defer-max (T13): only rescale when the tile max grew materially
  float mref = mrun;
  if (!__all(mx <= mrun + 8.0f)) {
    const float mnew = fmaxf(mrun, mx);
    const float corr = __builtin_amdgcn_exp2f(mrun - mnew);
    mrun = mnew; mref = mnew;
    srun *= corr;
#pragma unroll
    for (int r = 0; r < 16; ++r) { oacc[0][r] *= corr; oacc[1][r] *= corr; }
  }

  // ---- exp2 + partial rowsum (cross-lane sum deferred to epilogue)
  float psum = 0.0f;
#pragma unroll
  for (int r = 0; r < 16; ++r) {
    s0[r] = __builtin_amdgcn_exp2f(s0[r] - mref);
    s1[r] = __builtin_amdgcn_exp2f(s1[r] - mref);
    psum += s0[r] + s1[r];
  }
  srun += psum;

  // ---- P -> B-frag via pack + permlane32_swap (T12)
  upw pw[4];
#pragma unroll
  for (int cl = 0; cl < 2; ++cl) {
    {
      u32 a01 = pkbf(s0[8 * cl + 0], s0[8 * cl + 1]);
      u32 a23 = pkbf(s0[8 * cl + 2], s0[8 * cl + 3]);
      u32 b01 = pkbf(s0[8 * cl + 4], s0[8 * cl + 5]);
      u32 b23 = pkbf(s0[8 * cl + 6], s0[8 * cl + 7]);
      asm("v_permlane32_swap_b32 %0, %1" : "+v"(a01), "+v"(b01));
      asm("v_permlane32_swap_b32 %0, %1" : "+v"(a23), "+v"(b23));
      pw[cl].w[0] = a01; pw[cl].w[1] = a23; pw[cl].w[2] = b01; pw[cl].w[3] = b23;
    }
    {
      u32 a01 = pkbf(s1[8 * cl + 0], s1[8 * cl + 1]);
      u32 a23 = pkbf(s1[8 * cl + 2], s1[8 * cl + 3]);
      u32 b01 = pkbf(s1[8 * cl + 4], s1[8 * cl + 5]);
      u32 b23 = pkbf(s1[8 * cl + 6], s1[8 * cl + 7]);
      asm("v_permlane32_swap_b32 %0, %1" : "+v"(a01), "+v"(b01));
      asm("v_permlane32_swap_b32 %0, %1" : "+v"(a23), "+v"(b23));
      pw[2 + cl].w[0] = a01; pw[2 + cl].w[1] = a23; pw[2 + cl].w[2] = b01; pw[2 + cl].w[3] = b23;
    }
  }

  // ---- PV: O^T += V^T-frag x P-frag
  __builtin_amdgcn_s_setprio(1);
#pragma unroll
  for (int dh = 0; dh < 2; ++dh) {
    const char* vrow = vbase + (32 * dh + l31) * 128;
#pragma unroll
    for (int c = 0; c < 4; ++c) {
      bf16x8 vf = *reinterpret_cast<const bf16x8*>(vrow + (((2 * c + hi) * 16) ^ swz));
      oacc[dh] = __builtin_amdgcn_mfma_f32_32x32x16_bf16(vf, pw[c].v, oacc[dh], 0, 0, 0);
    }
  }
  __builtin_amdgcn_s_setprio(0);
}

// ---------------- causal flash attention: paired q-bands, shared KV stream ----------
// block = (bh, pair p): bands qt=15-p (H) and qt=p (L); 4 waves x 32 q rows per band.
__global__ __launch_bounds__(256, 2) void attn_kernel(const bf16* __restrict__ Qh,
                                                      const bf16* __restrict__ Kh,
                                                      const bf16* __restrict__ VhT,
                                                      bf16* __restrict__ aout) {
  __shared__ __align__(16) bf16 lK[2][64 * 64];
  __shared__ __align__(16) bf16 lVT[2][64 * 64];
  const int tid  = threadIdx.x;
  const int lane = tid & 63, wave = tid >> 6;
  const int l31  = lane & 31;
  const int hi   = lane >> 5;
  const int bid  = blockIdx.x;              // 0..511, linear: same-bh blocks land on one XCD
  const int bh   = bid & 63;
  const int p    = bid >> 6;                // 0..7
  const int qtH  = 15 - p, qtL = p;
  const int b    = bh >> 4, h = bh & 15;
  const int q0H  = qtH * 128 + wave * 32;
  const int q0L  = qtL * 128 + wave * 32;
  const size_t tb = (size_t)b * TT;
  const int swz  = (l31 & 7) << 4;

  // Q fragments for both bands, pre-scaled by 0.125*log2(e)
  const float QSCALE = 0.18033688011112042f;
  bf16x8 qfrH[4], qfrL[4];
  {
    const bf16* qrowH = Qh + ((size_t)bh * TT + q0H + l31) * HDIM;
    const bf16* qrowL = Qh + ((size_t)bh * TT + q0L + l31) * HDIM;
#pragma unroll
    for (int dc = 0; dc < 4; ++dc) {
      bf16x8 vH = *reinterpret_cast<const bf16x8*>(qrowH + dc * 16 + hi * 8);
      bf16x8 vL = *reinterpret_cast<const bf16x8*>(qrowL + dc * 16 + hi * 8);
      bf16x8 oH, oL;
#pragma unroll
      for (int j = 0; j < 8; ++j) {
        oH[j] = (bf16)((float)vH[j] * QSCALE);
        oL[j] = (bf16)((float)vL[j] * QSCALE);
      }
      qfrH[dc] = oH; qfrL[dc] = oL;
    }
  }

  f32x16 oaccH[2] = {}, oaccL[2] = {};
  float mH = -3e38f, sH = 0.0f, mL = -3e38f, sL = 0.0f;

  // staging (thread handles chunks tid and tid+256 of the 64x64 tiles)
  const int r0 = tid >> 3, sg = tid & 7;
  const bf16* kS0 = Kh + ((size_t)bh * TT + r0) * HDIM + (size_t)(sg ^ (r0 & 7)) * 8;
  const bf16* kS1 = Kh + ((size_t)bh * TT + 32 + r0) * HDIM + (size_t)(sg ^ (r0 & 7)) * 8;
  const bf16* vS0 = VhT + ((size_t)bh * HDIM + r0) * TT + (size_t)(sg ^ (r0 & 7)) * 8;
  const bf16* vS1 = VhT + ((size_t)bh * HDIM + 32 + r0) * TT + (size_t)(sg ^ (r0 & 7)) * 8;

  const int nkv = 2 * qtH + 2;

  // prologue: stage tile 0 into buf 0
  gload_lds16(kS0, &lK[0][tid * 8]);
  gload_lds16(kS1, &lK[0][(tid + 256) * 8]);
  gload_lds16(vS0, &lVT[0][tid * 8]);
  gload_lds16(vS1, &lVT[0][(tid + 256) * 8]);
  __syncthreads();

  int cur = 0;
  for (int t = 0; t < nkv; ++t) {
    const int kv0 = t * 64;
    if (t + 1 < nkv) {
      const int kvn = kv0 + 64;
      gload_lds16(kS0 + (size_t)kvn * HDIM, &lK[cur ^ 1][tid * 8]);
      gload_lds16(kS1 + (size_t)kvn * HDIM, &lK[cur ^ 1][(tid + 256) * 8]);
      gload_lds16(vS0 + kvn, &lVT[cur ^ 1][tid * 8]);
      gload_lds16(vS1 + kvn, &lVT[cur ^ 1][(tid + 256) * 8]);
    }

    const char* kbase = (const char*)&lK[cur][0];
    const char* vbase = (const char*)&lVT[cur][0];
    if (kv0 <= q0H + 31)
      attn_tile(kbase, vbase, qfrH, oaccH, mH, sH, kv0, q0H, l31, hi, swz);
    if (kv0 <= q0L + 31)
      attn_tile(kbase, vbase, qfrL, oaccL, mL, sL, kv0, q0L, l31, hi, swz);

    __syncthreads();   // drains prefetch + protects dbuf swap
    cur ^= 1;
  }

  // ---- epilogue: cross-lane rowsum, divide, store (both bands)
#pragma unroll
  for (int band = 0; band < 2; ++band) {
    const f32x16* oacc = band ? oaccL : oaccH;
    float sr = band ? sL : sH;
    sr += __shfl_xor(sr, 32);
    const float inv = 1.0f / sr;
    const int q = (band ? q0L : q0H) + l31;
    bf16* orow = aout + (tb + q) * (size_t)EMBED + h * HDIM;
#pragma unroll
    for (int dh = 0; dh < 2; ++dh)
#pragma unroll
      for (int rb = 0; rb < 4; ++rb) {
        bf16x4 o4;
#pragma unroll
        for (int k = 0; k < 4; ++k) o4[k] = (bf16)(oacc[dh][4 * rb + k] * inv);
        *reinterpret_cast<bf16x4*>(orow + 32 * dh + 8 * rb + 4 * hi) = o4;
      }
  }
}

extern "C" void kernel_launch(void* const* d_in, const int* in_sizes, int n_in,
                              void* d_out, int out_size, void* d_ws, size_t ws_size,
                              hipStream_t stream) {
  const float* x      = (const float*)d_in[0];
  const float* qkv_w  = (const float*)d_in[1];
  const float* qkv_b  = (const float*)d_in[2];
  const float* proj_w = (const float*)d_in[3];
  const float* proj_b = (const float*)d_in[4];
  float* out = (float*)d_out;

  const size_t QSZ = (size_t)BB * NHEAD * TT * HDIM;   // 8,388,608 elems per tensor
  char* ws = (char*)d_ws;
  bf16* xb    = (bf16*)ws;
  bf16* wqkv  = xb + (size_t)MTOK * EMBED;
  bf16* wproj = wqkv + (size_t)C3 * EMBED;
  bf16* Qh    = wproj + (size_t)EMBED * EMBED;
  bf16* Kh    = Qh + QSZ;
  bf16* VhT   = Kh + QSZ;
  bf16* aob   = xb;   // alias: xb dead after gemm_qkv

  const int NCVT = (MTOK * EMBED + C3 * EMBED + EMBED * EMBED) / 4;
  cvt_all<<<dim3((NCVT + 255) / 256), dim3(256), 0, stream>>>(x, qkv_w, proj_w,
                                                              xb, wqkv, wproj);

  gemm_qkv<<<dim3(C3 / 128, MTOK / 128), dim3(256), 0, stream>>>(xb, wqkv, qkv_b, Qh, Kh, VhT);

  attn_kernel<<<dim3(512), dim3(256), 0, stream>>>(Qh, Kh, VhT, aob);

  gemm_bt<<<dim3(EMBED / 128, MTOK / 128), dim3(256), 0, stream>>>(
      aob, wproj, proj_b, out, MTOK, EMBED, EMBED);
}